// Round 3
// baseline (4189.912 us; speedup 1.0000x reference)
//
#include <hip/hip_runtime.h>

#define NPTS 16384
#define DH 256
#define PH 4096
#define D2 512

// Static device scratch (do NOT rely on d_ws size; d_out is only 16 MB =
// 4,194,304 floats -> the real part of Gc). Fully rewritten every call.
__device__ float g_T[(size_t)2 * PH * D2];   // 16 MB: T = eB^T @ eA
__device__ float g_G[(size_t)NPTS * D2];     // 32 MB: G = eB @ T (d-major)

// ---------------------------------------------------------------------------
// Kernel 1: T = eB^T @ eA   (8192 x 512), eB/eA recomputed on the fly.
// Grid (128, 8): block computes T rows [q0,q0+32) (cos) & [4096+q0,..) (sin),
// cols [d0, d0+64). 256 threads, thread tile = 2q x {cos,sin} x 4d.
// ---------------------------------------------------------------------------
__global__ __launch_bounds__(256) void ker_T(const float* __restrict__ pts,
                                             const float* __restrict__ A,
                                             const float* __restrict__ B) {
    const int q0 = blockIdx.x * 32;
    const int d0 = blockIdx.y * 64;
    const int t  = threadIdx.x;
    const int ti = t & 15;   // d sub-tile: d = d0 + ti*4 + j
    const int tq = t >> 4;   // q sub-tile: q_local = tq*2 + r

    __shared__ __align__(16) float sc[32][32];  // cos(beta)[nn][qq]
    __shared__ __align__(16) float ss[32][32];  // sin(beta)[nn][qq]
    __shared__ __align__(16) float ea[32][64];  // eA chunk [nn][dd]

    float acc_c[2][4] = {{0,0,0,0},{0,0,0,0}};
    float acc_s[2][4] = {{0,0,0,0},{0,0,0,0}};

    const int qq_s = t & 31;
    const int qg   = q0 + qq_s;
    const float b0 = B[qg], b1 = B[PH + qg], b2 = B[2*PH + qg];
    const int dd_s = t & 63;
    const int kd   = (d0 + dd_s) & (DH - 1);
    const float a0 = A[kd], a1 = A[DH + kd], a2 = A[2*DH + kd];
    const bool use_cos = (d0 < DH);

    for (int c = 0; c < NPTS/32; ++c) {
        const int nb = c * 32;
        __syncthreads();  // previous inner-loop reads done
        #pragma unroll
        for (int u = 0; u < 4; ++u) {
            const int nn = (t >> 5) + 8*u;
            const float* pr = pts + (size_t)(nb + nn)*3;
            const float bet = pr[0]*b0 + pr[1]*b1 + pr[2]*b2;
            float s, co; __sincosf(bet, &s, &co);
            sc[nn][qq_s] = co; ss[nn][qq_s] = s;
        }
        #pragma unroll
        for (int u = 0; u < 8; ++u) {
            const int nn = (t >> 6) + 4*u;
            const float* pr = pts + (size_t)(nb + nn)*3;
            const float alp = pr[0]*a0 + pr[1]*a1 + pr[2]*a2;
            ea[nn][dd_s] = use_cos ? __cosf(alp) : __sinf(alp);
        }
        __syncthreads();
        #pragma unroll
        for (int nn = 0; nn < 32; ++nn) {
            const float2 c2 = *(const float2*)&sc[nn][tq*2];
            const float2 s2 = *(const float2*)&ss[nn][tq*2];
            const float4 e4 = *(const float4*)&ea[nn][ti*4];
            const float cr[2] = {c2.x, c2.y};
            const float sr[2] = {s2.x, s2.y};
            const float ej[4] = {e4.x, e4.y, e4.z, e4.w};
            #pragma unroll
            for (int r = 0; r < 2; ++r)
                #pragma unroll
                for (int j = 0; j < 4; ++j) {
                    acc_c[r][j] += cr[r]*ej[j];
                    acc_s[r][j] += sr[r]*ej[j];
                }
        }
    }
    #pragma unroll
    for (int r = 0; r < 2; ++r) {
        const int q = q0 + tq*2 + r;
        float4 vc = make_float4(acc_c[r][0], acc_c[r][1], acc_c[r][2], acc_c[r][3]);
        float4 vs = make_float4(acc_s[r][0], acc_s[r][1], acc_s[r][2], acc_s[r][3]);
        *(float4*)&g_T[(size_t)q*D2 + d0 + ti*4] = vc;
        *(float4*)&g_T[(size_t)(PH + q)*D2 + d0 + ti*4] = vs;
    }
}

// ---------------------------------------------------------------------------
// Kernel 2: G = eB @ T  (16384 x 512), written d-major into g_G.
// Grid (256, 8): block tile 64n x 64d, K = 8192 (4096 q, cos+sin rows of T).
// 256 threads, thread tile = 4n x 4d.
// ---------------------------------------------------------------------------
__global__ __launch_bounds__(256) void ker_G(const float* __restrict__ pts,
                                             const float* __restrict__ B) {
    const int n0 = blockIdx.x * 64;
    const int d0 = blockIdx.y * 64;
    const int t  = threadIdx.x;
    const int ti = t & 15;   // d = d0 + ti*4 + j
    const int tj = t >> 4;   // n_local = tj*4 + r

    __shared__ __align__(16) float scT[32][68];  // cos(beta)^T [qq][nn 0..63]
    __shared__ __align__(16) float ssT[32][68];  // 68 = 64 + 4 pad (16B rows)
    __shared__ __align__(16) float Tc[32][64];
    __shared__ __align__(16) float Ts[32][64];
    __shared__ __align__(16) float sp[64][3];

    if (t < 192) (&sp[0][0])[t] = pts[(size_t)n0*3 + t];

    float acc[4][4] = {{0,0,0,0},{0,0,0,0},{0,0,0,0},{0,0,0,0}};

    const int qq_s = t & 31;
    const int nn_0 = t >> 5;   // + 8u -> nn in [0,64)
    const int dd_s = t & 63;
    const int qr_0 = t >> 6;   // + 4u -> qq in [0,32)

    __syncthreads();  // sp ready

    for (int c = 0; c < PH/32; ++c) {
        const int qc = c * 32;
        #pragma unroll
        for (int u = 0; u < 8; ++u) {
            const int qq = qr_0 + 4*u;
            Tc[qq][dd_s] = g_T[(size_t)(qc + qq)*D2 + d0 + dd_s];
            Ts[qq][dd_s] = g_T[(size_t)(PH + qc + qq)*D2 + d0 + dd_s];
        }
        {
            const int qg = qc + qq_s;
            const float b0 = B[qg], b1 = B[PH + qg], b2 = B[2*PH + qg];
            #pragma unroll
            for (int u = 0; u < 8; ++u) {
                const int nn = nn_0 + 8*u;
                const float bet = sp[nn][0]*b0 + sp[nn][1]*b1 + sp[nn][2]*b2;
                float s, co; __sincosf(bet, &s, &co);
                scT[qq_s][nn] = co; ssT[qq_s][nn] = s;
            }
        }
        __syncthreads();
        #pragma unroll
        for (int qq = 0; qq < 32; ++qq) {
            const float4 c4 = *(const float4*)&scT[qq][tj*4];
            const float4 s4 = *(const float4*)&ssT[qq][tj*4];
            const float4 t4 = *(const float4*)&Tc[qq][ti*4];
            const float4 u4 = *(const float4*)&Ts[qq][ti*4];
            const float cr[4] = {c4.x, c4.y, c4.z, c4.w};
            const float sr[4] = {s4.x, s4.y, s4.z, s4.w};
            const float tj_[4] = {t4.x, t4.y, t4.z, t4.w};
            const float uj_[4] = {u4.x, u4.y, u4.z, u4.w};
            #pragma unroll
            for (int r = 0; r < 4; ++r)
                #pragma unroll
                for (int j = 0; j < 4; ++j) {
                    acc[r][j] += cr[r]*tj_[j];
                    acc[r][j] += sr[r]*uj_[j];
                }
        }
        __syncthreads();
    }
    #pragma unroll
    for (int r = 0; r < 4; ++r) {
        float4 v = make_float4(acc[r][0], acc[r][1], acc[r][2], acc[r][3]);
        *(float4*)&g_G[(size_t)(n0 + tj*4 + r)*D2 + d0 + ti*4] = v;
    }
}

// ---------------------------------------------------------------------------
// Kernel 3: epilogue. Gc = (Gr + i*Gi) * conj(e^{i alpha}) (|e^{i a}|=1, so
// divide == conj-mult; rotation preserves row norm -> scale = 16/||G row||).
// Output = REAL PART only (harness stores complex64 ref cast to float32):
// out[n*256 + k] = Re(Gc[n][k]) * scale.
// ---------------------------------------------------------------------------
__global__ __launch_bounds__(256) void ker_fin(const float* __restrict__ pts,
                                               const float* __restrict__ A,
                                               float* __restrict__ out) {
    const int n = blockIdx.x;
    const int k = threadIdx.x;  // 0..255
    const float p0 = pts[(size_t)n*3], p1 = pts[(size_t)n*3+1], p2 = pts[(size_t)n*3+2];
    const float alp = p0*A[k] + p1*A[DH + k] + p2*A[2*DH + k];
    float sa, ca; __sincosf(alp, &sa, &ca);
    const float Gr = g_G[(size_t)n*D2 + k];
    const float Gi = g_G[(size_t)n*D2 + DH + k];
    const float Re = Gr*ca + Gi*sa;
    float nr = Gr*Gr + Gi*Gi;
    #pragma unroll
    for (int off = 32; off > 0; off >>= 1) nr += __shfl_down(nr, off, 64);
    __shared__ float wsum[4];
    if ((k & 63) == 0) wsum[k >> 6] = nr;
    __syncthreads();
    const float total = wsum[0] + wsum[1] + wsum[2] + wsum[3];
    const float scale = 16.0f * rsqrtf(total);
    out[(size_t)n*DH + k] = Re * scale;
}

extern "C" void kernel_launch(void* const* d_in, const int* in_sizes, int n_in,
                              void* d_out, int out_size, void* d_ws, size_t ws_size,
                              hipStream_t stream) {
    const float* pts = (const float*)d_in[0];
    const float* A   = (const float*)d_in[1];
    const float* B   = (const float*)d_in[2];
    float* out = (float*)d_out;
    (void)d_ws; (void)ws_size; (void)out_size;

    ker_T<<<dim3(128, 8), 256, 0, stream>>>(pts, A, B);
    ker_G<<<dim3(256, 8), 256, 0, stream>>>(pts, B);
    ker_fin<<<16384, 256, 0, stream>>>(pts, A, out);
}

// Round 4
// 404.689 us; speedup vs baseline: 10.3534x; 10.3534x over previous
//
#include <hip/hip_runtime.h>

#define NPTS 16384
#define DH 256
#define PH 4096
#define D2 512
#define LDA 40   // padded K-stride (halfs): 80B rows -> 16B-aligned frags, ~2-way banks

typedef _Float16 f16;
typedef _Float16 f16x4 __attribute__((ext_vector_type(4)));
typedef _Float16 f16x8 __attribute__((ext_vector_type(8)));
typedef float f32x4 __attribute__((ext_vector_type(4)));

// Static device scratch (d_out is only 16 MB; d_ws size unknown -> module-level).
// All buffers fully rewritten before use on every call (deterministic).
__device__ f16   g_eAt[D2][NPTS];       // 16 MB: eA^T fp16 [d][n]
__device__ f16   g_Tt[4][D2][2*PH];     // 32 MB: K-split partials of T^T [z][d][trow]
__device__ f16   g_Ts[D2][2*PH];        //  8 MB: summed T^T
__device__ float g_G[2][NPTS][D2];      // 64 MB: K-split partials of G

// ---------------------------------------------------------------------------
// eA^T precompute: alpha[n][dd] = pts[n]·A[:,dd]; rows dd=cos, dd+256=sin.
// ---------------------------------------------------------------------------
__global__ __launch_bounds__(256) void ker_pre(const float* __restrict__ pts,
                                               const float* __restrict__ A) {
    const int dd = blockIdx.x;           // 0..255
    const int t  = threadIdx.x;
    const float a0 = A[dd], a1 = A[DH + dd], a2 = A[2*DH + dd];
    for (int i = 0; i < NPTS/256; ++i) {
        const int n = i*256 + t;
        const float* pr = pts + (size_t)n*3;
        float s, co; __sincosf(pr[0]*a0 + pr[1]*a1 + pr[2]*a2, &s, &co);
        g_eAt[dd][n]      = (f16)co;
        g_eAt[DH + dd][n] = (f16)s;
    }
}

// ---------------------------------------------------------------------------
// GEMM1: T^T[d][q·cs] = sum_n eA[n][d]·eB[n][q·cs], fp16 MFMA 16x16x32.
// Grid (64 Mb, 2 Nb, 4 Ks), 512 thr = 8 waves (2M x 4N), wave-tile 64x64.
// Block tile: M=128 rows (64 q as cos+sin), N=256 d-cols, K-chunk 32 n.
// A (eB) staged via on-the-fly sincos; B (eA^T) loaded fp16 from g_eAt.
// ---------------------------------------------------------------------------
__global__ __launch_bounds__(512) void ker_T(const float* __restrict__ pts,
                                             const float* __restrict__ B) {
    const int q0 = blockIdx.x * 64;
    const int d0 = blockIdx.y * 256;
    const int ks = blockIdx.z;                 // n-range [ks*4096, +4096)
    const int t  = threadIdx.x;
    const int lane = t & 63, wid = t >> 6;
    const int wm = wid >> 2, wn = wid & 3;

    __shared__ f16 Al[128][LDA];   // [q·cs][n-chunk]
    __shared__ f16 Bl[256][LDA];   // [d][n-chunk]

    f32x4 acc[4][4];
    #pragma unroll
    for (int a = 0; a < 4; ++a)
        #pragma unroll
        for (int b = 0; b < 4; ++b) acc[a][b] = (f32x4){0.f, 0.f, 0.f, 0.f};

    // trig staging map: qq = t>>3 (0..63), nn0 = (t&7)*4
    const int qq  = t >> 3;
    const int nn0 = (t & 7) * 4;
    const float b0 = B[q0+qq], b1 = B[PH+q0+qq], b2 = B[2*PH+q0+qq];
    // B staging map: dd = t>>1 (0..255), k0 = (t&1)*16
    const int dd = t >> 1;
    const int k0 = (t & 1) * 16;

    const int mrow = wm*64 + (lane & 15);
    const int ncol = wn*64 + (lane & 15);
    const int kof  = (lane >> 4) * 8;

    for (int c = 0; c < 128; ++c) {
        const int nb = ks*4096 + c*32;
        __syncthreads();
        {   // A stage: 4 consecutive pts rows = 12 contiguous floats = 3 float4
            const float* pbase = pts + (size_t)(nb + nn0)*3;
            const float4 pA4 = *(const float4*)(pbase);
            const float4 pB4 = *(const float4*)(pbase + 4);
            const float4 pC4 = *(const float4*)(pbase + 8);
            const float px[4] = {pA4.x, pA4.w, pB4.z, pC4.y};
            const float py[4] = {pA4.y, pB4.x, pB4.w, pC4.z};
            const float pz[4] = {pA4.z, pB4.y, pC4.x, pC4.w};
            f16x4 vc, vs;
            #pragma unroll
            for (int u = 0; u < 4; ++u) {
                float s, co; __sincosf(px[u]*b0 + py[u]*b1 + pz[u]*b2, &s, &co);
                vc[u] = (f16)co; vs[u] = (f16)s;
            }
            *(f16x4*)&Al[qq][nn0]      = vc;
            *(f16x4*)&Al[64 + qq][nn0] = vs;
        }
        {   // B stage: 16 halfs from eA_t row
            const f16* src = &g_eAt[d0 + dd][nb + k0];
            *(f16x8*)&Bl[dd][k0]     = *(const f16x8*)src;
            *(f16x8*)&Bl[dd][k0 + 8] = *(const f16x8*)(src + 8);
        }
        __syncthreads();
        f16x8 af[4], bf[4];
        #pragma unroll
        for (int mf = 0; mf < 4; ++mf) af[mf] = *(const f16x8*)&Al[mrow + mf*16][kof];
        #pragma unroll
        for (int nf = 0; nf < 4; ++nf) bf[nf] = *(const f16x8*)&Bl[ncol + nf*16][kof];
        #pragma unroll
        for (int mf = 0; mf < 4; ++mf)
            #pragma unroll
            for (int nf = 0; nf < 4; ++nf)
                acc[mf][nf] = __builtin_amdgcn_mfma_f32_16x16x32_f16(
                    af[mf], bf[nf], acc[mf][nf], 0, 0, 0);
    }
    // epilogue: D row=(l>>4)*4+j (M=q·cs), col=l&15 (N=d) -> T^T[d][trow]
    #pragma unroll
    for (int mf = 0; mf < 4; ++mf) {
        const int mbase = wm*64 + mf*16 + (lane >> 4)*4;
        const int trow  = (mbase >= 64 ? PH : 0) + q0 + (mbase & 63);
        #pragma unroll
        for (int nf = 0; nf < 4; ++nf) {
            const int d = d0 + wn*64 + nf*16 + (lane & 15);
            f16x4 v;
            #pragma unroll
            for (int j = 0; j < 4; ++j) v[j] = (f16)acc[mf][nf][j];
            *(f16x4*)&g_Tt[ks][d][trow] = v;
        }
    }
}

// ---------------------------------------------------------------------------
// Sum the 4 K-split T partials -> g_Ts (fp16).
// ---------------------------------------------------------------------------
__global__ __launch_bounds__(256) void ker_tsum() {
    const size_t i = ((size_t)blockIdx.x*256 + threadIdx.x) * 8;
    const f16* p0 = &g_Tt[0][0][0];
    const f16* p1 = &g_Tt[1][0][0];
    const f16* p2 = &g_Tt[2][0][0];
    const f16* p3 = &g_Tt[3][0][0];
    const f16x8 a = *(const f16x8*)(p0+i), b = *(const f16x8*)(p1+i);
    const f16x8 cc = *(const f16x8*)(p2+i), d = *(const f16x8*)(p3+i);
    f16x8 r;
    #pragma unroll
    for (int j = 0; j < 8; ++j)
        r[j] = (f16)((float)a[j] + (float)b[j] + (float)cc[j] + (float)d[j]);
    *(f16x8*)(&g_Ts[0][0] + i) = r;
}

// ---------------------------------------------------------------------------
// GEMM2: G[n][d] = sum_q (cos(beta)·Ts[q][d] + sin(beta)·Ts[4096+q][d]).
// Grid (128 nb, 2 Nb, 2 Ks), 512 thr = 8 waves (2M x 4N), wave-tile 64x64.
// Block tile: M=128 n, N=256 d, K-chunk 32 q (cos+sin = K 64 per chunk).
// ---------------------------------------------------------------------------
__global__ __launch_bounds__(512) void ker_G(const float* __restrict__ pts,
                                             const float* __restrict__ B) {
    const int n0 = blockIdx.x * 128;
    const int d0 = blockIdx.y * 256;
    const int ks = blockIdx.z;                 // q-range [ks*2048, +2048)
    const int t  = threadIdx.x;
    const int lane = t & 63, wid = t >> 6;
    const int wm = wid >> 2, wn = wid & 3;

    __shared__ f16 Ac[128][LDA], As[128][LDA];   // eB cos/sin [n][q-chunk]
    __shared__ f16 Bc[256][LDA], Bs[256][LDA];   // Ts cols    [d][q-chunk]

    f32x4 acc[4][4];
    #pragma unroll
    for (int a = 0; a < 4; ++a)
        #pragma unroll
        for (int b = 0; b < 4; ++b) acc[a][b] = (f32x4){0.f, 0.f, 0.f, 0.f};

    // trig staging map: nn = t>>2 (0..127) fixed pts row; qq0 = (t&3)*8
    const int nn  = t >> 2;
    const int qq0 = (t & 3) * 8;
    const float px = pts[(size_t)(n0+nn)*3];
    const float py = pts[(size_t)(n0+nn)*3 + 1];
    const float pz = pts[(size_t)(n0+nn)*3 + 2];
    // B staging map
    const int dd = t >> 1;
    const int k0 = (t & 1) * 16;

    const int mrow = wm*64 + (lane & 15);
    const int ncol = wn*64 + (lane & 15);
    const int kof  = (lane >> 4) * 8;

    for (int c = 0; c < 64; ++c) {
        const int qk = ks*2048 + c*32;
        __syncthreads();
        {   // A stage: 8 betas for fixed n-row
            const int qg = qk + qq0;
            const float4 bx0 = *(const float4*)&B[qg];
            const float4 bx1 = *(const float4*)&B[qg + 4];
            const float4 by0 = *(const float4*)&B[PH + qg];
            const float4 by1 = *(const float4*)&B[PH + qg + 4];
            const float4 bz0 = *(const float4*)&B[2*PH + qg];
            const float4 bz1 = *(const float4*)&B[2*PH + qg + 4];
            const float bx[8] = {bx0.x,bx0.y,bx0.z,bx0.w, bx1.x,bx1.y,bx1.z,bx1.w};
            const float by[8] = {by0.x,by0.y,by0.z,by0.w, by1.x,by1.y,by1.z,by1.w};
            const float bz[8] = {bz0.x,bz0.y,bz0.z,bz0.w, bz1.x,bz1.y,bz1.z,bz1.w};
            f16x8 vc, vs;
            #pragma unroll
            for (int u = 0; u < 8; ++u) {
                float s, co; __sincosf(px*bx[u] + py*by[u] + pz*bz[u], &s, &co);
                vc[u] = (f16)co; vs[u] = (f16)s;
            }
            *(f16x8*)&Ac[nn][qq0] = vc;
            *(f16x8*)&As[nn][qq0] = vs;
        }
        {   // B stage: Ts rows (cos cols qk.., sin cols PH+qk..)
            const f16* sc_ = &g_Ts[d0 + dd][qk + k0];
            *(f16x8*)&Bc[dd][k0]     = *(const f16x8*)sc_;
            *(f16x8*)&Bc[dd][k0 + 8] = *(const f16x8*)(sc_ + 8);
            const f16* ss_ = &g_Ts[d0 + dd][PH + qk + k0];
            *(f16x8*)&Bs[dd][k0]     = *(const f16x8*)ss_;
            *(f16x8*)&Bs[dd][k0 + 8] = *(const f16x8*)(ss_ + 8);
        }
        __syncthreads();
        f16x8 a1[4], a2[4], b1[4], b2[4];
        #pragma unroll
        for (int mf = 0; mf < 4; ++mf) {
            a1[mf] = *(const f16x8*)&Ac[mrow + mf*16][kof];
            a2[mf] = *(const f16x8*)&As[mrow + mf*16][kof];
        }
        #pragma unroll
        for (int nf = 0; nf < 4; ++nf) {
            b1[nf] = *(const f16x8*)&Bc[ncol + nf*16][kof];
            b2[nf] = *(const f16x8*)&Bs[ncol + nf*16][kof];
        }
        #pragma unroll
        for (int mf = 0; mf < 4; ++mf)
            #pragma unroll
            for (int nf = 0; nf < 4; ++nf) {
                acc[mf][nf] = __builtin_amdgcn_mfma_f32_16x16x32_f16(
                    a1[mf], b1[nf], acc[mf][nf], 0, 0, 0);
                acc[mf][nf] = __builtin_amdgcn_mfma_f32_16x16x32_f16(
                    a2[mf], b2[nf], acc[mf][nf], 0, 0, 0);
            }
    }
    // epilogue -> g_G[ks][n][d] fp32
    #pragma unroll
    for (int mf = 0; mf < 4; ++mf) {
        const int nbase = n0 + wm*64 + mf*16 + (lane >> 4)*4;
        #pragma unroll
        for (int nf = 0; nf < 4; ++nf) {
            const int d = d0 + wn*64 + nf*16 + (lane & 15);
            #pragma unroll
            for (int j = 0; j < 4; ++j)
                g_G[ks][nbase + j][d] = acc[mf][nf][j];
        }
    }
}

// ---------------------------------------------------------------------------
// Epilogue: Gc = (Gr + i·Gi)·conj(e^{i alpha}) (|e^{ia}|=1 -> divide == conj
// mult; rotation preserves row norm -> scale = 16/||G row||). Output = real
// part only (harness stores complex64 ref cast to float32): 16384x256.
// ---------------------------------------------------------------------------
__global__ __launch_bounds__(256) void ker_fin(const float* __restrict__ pts,
                                               const float* __restrict__ A,
                                               float* __restrict__ out) {
    const int n = blockIdx.x;
    const int k = threadIdx.x;  // 0..255
    const float p0 = pts[(size_t)n*3], p1 = pts[(size_t)n*3+1], p2 = pts[(size_t)n*3+2];
    const float alp = p0*A[k] + p1*A[DH + k] + p2*A[2*DH + k];
    float sa, ca; __sincosf(alp, &sa, &ca);
    const float Gr = g_G[0][n][k]      + g_G[1][n][k];
    const float Gi = g_G[0][n][DH + k] + g_G[1][n][DH + k];
    const float Re = Gr*ca + Gi*sa;
    float nr = Gr*Gr + Gi*Gi;
    #pragma unroll
    for (int off = 32; off > 0; off >>= 1) nr += __shfl_down(nr, off, 64);
    __shared__ float wsum[4];
    if ((k & 63) == 0) wsum[k >> 6] = nr;
    __syncthreads();
    const float total = wsum[0] + wsum[1] + wsum[2] + wsum[3];
    const float scale = 16.0f * rsqrtf(total);
    out[(size_t)n*DH + k] = Re * scale;
}

extern "C" void kernel_launch(void* const* d_in, const int* in_sizes, int n_in,
                              void* d_out, int out_size, void* d_ws, size_t ws_size,
                              hipStream_t stream) {
    const float* pts = (const float*)d_in[0];
    const float* A   = (const float*)d_in[1];
    const float* B   = (const float*)d_in[2];
    float* out = (float*)d_out;
    (void)d_ws; (void)ws_size; (void)out_size;

    ker_pre <<<256, 256, 0, stream>>>(pts, A);
    ker_T   <<<dim3(64, 2, 4), 512, 0, stream>>>(pts, B);
    ker_tsum<<<2048, 256, 0, stream>>>();
    ker_G   <<<dim3(128, 2, 2), 512, 0, stream>>>(pts, B);
    ker_fin <<<16384, 256, 0, stream>>>(pts, A, out);
}